// Round 10
// baseline (8418.378 us; speedup 1.0000x reference)
//
#include <hip/hip_runtime.h>
#include <stdint.h>

#define B_ 64
#define T_ 512
#define IN_ 128
#define H_ 256
#define G_ 768
#define M0_ (B_*T_)   // 32768

typedef _Float16 f16;
typedef _Float16 f16x2 __attribute__((ext_vector_type(2)));
typedef _Float16 half8 __attribute__((ext_vector_type(8)));
typedef float f32x4 __attribute__((ext_vector_type(4)));

// ---------------- projection GEMM: xg[dir][m][n] = A[m][:]·W[dir][n][:] + bias[dir][n] ----------------
// A: M0 x K (f32 if AF32 else f16) row-major; W: 2 x 768 x K f32 (B^T layout); out: 2 x M0 x 768 f16
template<bool AF32>
__global__ __launch_bounds__(256) void k_proj(
    const float* __restrict__ Af, const f16* __restrict__ Ah,
    const float* __restrict__ W, const float* __restrict__ bias,
    f16* __restrict__ out, int K)
{
  int dir = blockIdx.z;
  const float* Wd = W + (size_t)dir*G_*K;
  const float* bd = bias + dir*G_;
  f16* outd = out + (size_t)dir*M0_*G_;
  int m0 = blockIdx.x*128, n0 = blockIdx.y*128;
  int tid = threadIdx.x, lane = tid & 63, wv = tid >> 6;
  int wm = wv >> 1, wn = wv & 1;
  int l15 = lane & 15, quad = lane >> 4;

  __shared__ f16 As[128][72];   // +8 pad breaks bank conflicts
  __shared__ f16 Ws[128][72];

  f32x4 acc[4][4];
  #pragma unroll
  for (int i = 0; i < 4; i++)
    #pragma unroll
    for (int j = 0; j < 4; j++) acc[i][j] = (f32x4){0.f,0.f,0.f,0.f};

  int lr = tid >> 3, lk = (tid & 7) * 8;
  for (int k0 = 0; k0 < K; k0 += 64){
    #pragma unroll
    for (int it = 0; it < 4; it++){
      int row = lr + it*32;
      // A tile
      if (AF32){
        const float* p = &Af[(size_t)(m0+row)*K + k0 + lk];
        float4 v0 = *(const float4*)p;
        float4 v1 = *(const float4*)(p + 4);
        *(half8*)&As[row][lk] = (half8){(f16)v0.x,(f16)v0.y,(f16)v0.z,(f16)v0.w,
                                        (f16)v1.x,(f16)v1.y,(f16)v1.z,(f16)v1.w};
      } else {
        *(uint4*)&As[row][lk] = *(const uint4*)&Ah[(size_t)(m0+row)*K + k0 + lk];
      }
      // W tile (always f32 -> f16)
      {
        const float* p = &Wd[(size_t)(n0+row)*K + k0 + lk];
        float4 v0 = *(const float4*)p;
        float4 v1 = *(const float4*)(p + 4);
        *(half8*)&Ws[row][lk] = (half8){(f16)v0.x,(f16)v0.y,(f16)v0.z,(f16)v0.w,
                                        (f16)v1.x,(f16)v1.y,(f16)v1.z,(f16)v1.w};
      }
    }
    __syncthreads();
    #pragma unroll
    for (int kk = 0; kk < 64; kk += 32){
      half8 af[4], bf[4];
      #pragma unroll
      for (int mi = 0; mi < 4; mi++) af[mi] = *(const half8*)&As[wm*64 + mi*16 + l15][kk + quad*8];
      #pragma unroll
      for (int ni = 0; ni < 4; ni++) bf[ni] = *(const half8*)&Ws[wn*64 + ni*16 + l15][kk + quad*8];
      #pragma unroll
      for (int mi = 0; mi < 4; mi++)
        #pragma unroll
        for (int ni = 0; ni < 4; ni++)
          acc[mi][ni] = __builtin_amdgcn_mfma_f32_16x16x32_f16(af[mi], bf[ni], acc[mi][ni], 0, 0, 0);
    }
    __syncthreads();
  }
  #pragma unroll
  for (int mi = 0; mi < 4; mi++){
    #pragma unroll
    for (int ni = 0; ni < 4; ni++){
      int m = m0 + wm*64 + mi*16 + quad*4;
      int n = n0 + wn*64 + ni*16 + l15;
      float bn = bd[n];
      #pragma unroll
      for (int r = 0; r < 4; r++)
        outd[(size_t)(m+r)*G_ + n] = (f16)(acc[mi][ni][r] + bn);
    }
  }
}

// ---------------- batched-M persistent-register GRU ----------------
// The key fix: broadcast-M wasted 15/16 of every MFMA. Instead the 16 M-rows carry 16
// DIFFERENT BATCHES (all batches share Whh per layer/dir). One WG per (batch-group of 16,
// dir): grid (4,2) = 8 WGs, 256 thr (4 waves) @ waves_per_eu(1,1) -> 512 regs/wave.
// Wave wv owns units [wv*64, wv*64+64) x 3 gates = 12 N-tiles x 8 k-frags = 96 half8
// B-frags = 384 regs -- EXACTLY r6's proven-resident footprint (VGPR=256, no spill).
// Per step: 8 k-frags x 12 MFMAs = 96 MFMA/wave covering all 16 batches (16x the useful
// work of broadcast-M at the same MFMA count). A-frags: lane(m=lane&15 -> batch,
// kg=lane>>4 -> k-group) reads h[m][kf*32+kg*8] from a 16x264-padded LDS h matrix.
// C/D layout (col=lane&15 -> unit, row=kg*4+r -> batch): each lane owns 16 (batch,unit)
// pairs for gate math, fully local (no shuffles, no redistribution). bhh folds into the
// MFMA C-init. xg: 48 scalar f16 loads/lane prefetched one FULL step ahead (issued at
// step tail, consumed after next step's MFMA block; barrier is lgkm-only so the loads
// stay in flight). One raw barrier per step; x2 unrolled ping-pong LDS h buffers.
__global__ __launch_bounds__(256) __attribute__((amdgpu_waves_per_eu(1, 1)))
void k_rnn(
    const f16* __restrict__ xg, const float* __restrict__ whh,
    const float* __restrict__ bhh, f16* __restrict__ y)
{
  int bg = blockIdx.x, dir = blockIdx.y;
  int b0 = bg << 4;                       // batch group base
  int tid = threadIdx.x, lane = tid & 63, wv = tid >> 6;
  int l15 = lane & 15, kg = lane >> 4;    // l15: A-row(batch) & B-col(unit); kg: k-group

  const f16* cxg = xg + (size_t)dir*M0_*G_;
  const float* wbase = whh + (size_t)dir*G_*H_;
  const float* bh = bhh + dir*G_;

  __shared__ __align__(16) f16 h0[16][264];   // +8 pad: A-read row-stride 528B
  __shared__ __align__(16) f16 h1[16][264];

  // ---- resident B-fragments: tile t = gate*4 + coltile (units wv*64+coltile*16+l15) ----
  half8 wf[96];
  #pragma unroll
  for (int t = 0; t < 12; t++){
    int g = t >> 2, c = t & 3;
    const float* wrow = wbase + (size_t)(g*256 + wv*64 + c*16 + l15)*H_;
    #pragma unroll
    for (int kf = 0; kf < 8; kf++){
      const float4* p = (const float4*)(wrow + kf*32 + kg*8);
      float4 v0 = p[0], v1 = p[1];
      wf[t*8+kf] = (half8){(f16)v0.x,(f16)v0.y,(f16)v0.z,(f16)v0.w,
                           (f16)v1.x,(f16)v1.y,(f16)v1.z,(f16)v1.w};
    }
  }

  // per-tile bias (same for all 16 batches of a column) -> folded into MFMA C-init
  float bias_[12];
  #pragma unroll
  for (int t = 0; t < 12; t++){
    int g = t >> 2, c = t & 3;
    bias_[t] = bh[g*256 + wv*64 + c*16 + l15];
  }

  for (int idx = tid; idx < 16*264; idx += 256) ((f16*)h0)[idx] = (f16)0.f;
  __syncthreads();

  // xg prefetch: lane's 16 (batch m = kg*4+r, unit u = wv*64+c*16+l15) triples
  f16 xr_[16], xz_[16], xn_[16];
  {
    int t0 = dir ? (T_-1) : 0;
    #pragma unroll
    for (int r = 0; r < 4; r++){
      const f16* p = cxg + ((size_t)(b0 + kg*4 + r)*T_ + t0)*G_ + wv*64 + l15;
      #pragma unroll
      for (int c = 0; c < 4; c++){
        xr_[r*4+c] = p[c*16];
        xz_[r*4+c] = p[256 + c*16];
        xn_[r*4+c] = p[512 + c*16];
      }
    }
  }

// TT: this step's time index; TN: next step's (xg reload target)
#define RSTEP(SRC, DST, TT, TN)                                                 \
  {                                                                             \
    f32x4 acc[12];                                                              \
    _Pragma("unroll")                                                           \
    for (int kf = 0; kf < 8; kf++){                                             \
      half8 a = *(const half8*)&SRC[l15][kf*32 + kg*8];                         \
      _Pragma("unroll")                                                         \
      for (int t = 0; t < 12; t++){                                             \
        if (kf == 0)                                                            \
          acc[t] = __builtin_amdgcn_mfma_f32_16x16x32_f16(a, wf[t*8],           \
                     (f32x4){bias_[t],bias_[t],bias_[t],bias_[t]}, 0, 0, 0);    \
        else                                                                    \
          acc[t] = __builtin_amdgcn_mfma_f32_16x16x32_f16(a, wf[t*8+kf],        \
                     acc[t], 0, 0, 0);                                          \
      }                                                                         \
    }                                                                           \
    _Pragma("unroll")                                                           \
    for (int r = 0; r < 4; r++){                                                \
      _Pragma("unroll")                                                         \
      for (int c = 0; c < 4; c++){                                              \
        float sr = acc[c][r];          /* includes br (C-init) */               \
        float sz = acc[4+c][r];        /* includes bz */                        \
        float sn = acc[8+c][r];        /* includes bn */                        \
        float hprev = (float)SRC[kg*4+r][wv*64 + c*16 + l15];                   \
        float ar = (float)xr_[r*4+c] + sr; ar = fminf(fmaxf(ar,-30.f),30.f);    \
        float az = (float)xz_[r*4+c] + sz; az = fminf(fmaxf(az,-30.f),30.f);    \
        float rg = 1.f/(1.f + __expf(-ar));                                     \
        float zg = 1.f/(1.f + __expf(-az));                                     \
        float an = (float)xn_[r*4+c] + rg*sn; an = fminf(fmaxf(an,-15.f),15.f); \
        float e_ = __expf(2.f*an);                                              \
        float nn = (e_ - 1.f)/(e_ + 1.f);                                       \
        float hnew = (1.f - zg)*nn + zg*hprev;                                  \
        DST[kg*4+r][wv*64 + c*16 + l15] = (f16)hnew;                            \
        y[((size_t)(b0 + kg*4 + r)*T_ + (TT))*512 + dir*256 + wv*64 + c*16 + l15] \
            = (f16)hnew;                                                        \
      }                                                                         \
    }                                                                           \
    _Pragma("unroll")                                                           \
    for (int r = 0; r < 4; r++){     /* reload xg for NEXT step (full-step hide) */ \
      const f16* p = cxg + ((size_t)(b0 + kg*4 + r)*T_ + (TN))*G_ + wv*64 + l15;\
      _Pragma("unroll")                                                         \
      for (int c = 0; c < 4; c++){                                              \
        xr_[r*4+c] = p[c*16];                                                   \
        xz_[r*4+c] = p[256 + c*16];                                             \
        xn_[r*4+c] = p[512 + c*16];                                             \
      }                                                                         \
    }                                                                           \
    asm volatile("s_waitcnt lgkmcnt(0)\n\ts_barrier" ::: "memory");             \
  }

  for (int s = 0; s < T_; s += 2){
    int ttA = dir ? (T_-1-s) : s;
    int ttB = dir ? (T_-2-s) : (s+1);
    int s2c = (s + 2 < T_) ? (s + 2) : (T_ - 1);   // clamped dummy on last iter
    int ttC = dir ? (T_-1-s2c) : s2c;

    RSTEP(h0, h1, ttA, ttB)
    RSTEP(h1, h0, ttB, ttC)
  }
#undef RSTEP
}

// ---------------- MLP head: one WG per batch, all f32 ----------------
__global__ __launch_bounds__(256) void k_head(
    const f16* __restrict__ y,
    const float* __restrict__ W1, const float* __restrict__ b1,
    const float* __restrict__ W2, const float* __restrict__ b2,
    const float* __restrict__ W3, const float* __restrict__ b3,
    const float* __restrict__ W4, const float* __restrict__ b4,
    float* __restrict__ out)
{
  int b = blockIdx.x, tid = threadIdx.x;
  __shared__ float a0[512], a1[128], a2[64], a3[256];
  const f16* yr = y + ((size_t)b*T_ + (T_-1))*512;
  a0[tid] = (float)yr[tid]; a0[tid+256] = (float)yr[tid+256];
  __syncthreads();
  if (tid < 128){
    float s = b1[tid];
    const float4* w = (const float4*)(W1 + (size_t)tid*512);
    #pragma unroll 8
    for (int c = 0; c < 128; c++){
      float4 v = w[c];
      s += v.x*a0[c*4] + v.y*a0[c*4+1] + v.z*a0[c*4+2] + v.w*a0[c*4+3];
    }
    a1[tid] = fmaxf(s, 0.f);
  }
  __syncthreads();
  if (tid < 64){
    float s = b2[tid];
    const float4* w = (const float4*)(W2 + (size_t)tid*128);
    #pragma unroll
    for (int c = 0; c < 32; c++){
      float4 v = w[c];
      s += v.x*a1[c*4] + v.y*a1[c*4+1] + v.z*a1[c*4+2] + v.w*a1[c*4+3];
    }
    a2[tid] = fmaxf(s, 0.f);
  }
  __syncthreads();
  if (tid < 256){
    float s = b3[tid];
    const float4* w = (const float4*)(W3 + (size_t)tid*64);
    #pragma unroll
    for (int c = 0; c < 16; c++){
      float4 v = w[c];
      s += v.x*a2[c*4] + v.y*a2[c*4+1] + v.z*a2[c*4+2] + v.w*a2[c*4+3];
    }
    a3[tid] = fmaxf(s, 0.f);
  }
  __syncthreads();
  if (tid < 50){
    float s = b4[tid];
    const float4* w = (const float4*)(W4 + (size_t)tid*256);
    #pragma unroll
    for (int c = 0; c < 64; c++){
      float4 v = w[c];
      s += v.x*a3[c*4] + v.y*a3[c*4+1] + v.z*a3[c*4+2] + v.w*a3[c*4+3];
    }
    out[b*50 + tid] = s;
  }
}

extern "C" void kernel_launch(void* const* d_in, const int* in_sizes, int n_in,
                              void* d_out, int out_size, void* d_ws, size_t ws_size,
                              hipStream_t stream)
{
  const float* x    = (const float*)d_in[0];
  const float* Wih0 = (const float*)d_in[1];
  const float* Whh0 = (const float*)d_in[2];
  const float* bih0 = (const float*)d_in[3];
  const float* bhh0 = (const float*)d_in[4];
  const float* Wih  = (const float*)d_in[5];
  const float* Whh  = (const float*)d_in[6];
  const float* bih  = (const float*)d_in[7];
  const float* bhh  = (const float*)d_in[8];
  const float* W1 = (const float*)d_in[9];
  const float* b1 = (const float*)d_in[10];
  const float* W2 = (const float*)d_in[11];
  const float* b2 = (const float*)d_in[12];
  const float* W3 = (const float*)d_in[13];
  const float* b3 = (const float*)d_in[14];
  const float* W4 = (const float*)d_in[15];
  const float* b4 = (const float*)d_in[16];

  char* ws = (char*)d_ws;
  f16* xg = (f16*)ws;                          // 2*M0*768*2 = 100,663,296 B
  f16* y  = (f16*)(ws + 100663296ull);         //   M0*512*2 =  33,554,432 B
  // total exactly 128 MiB; nothing written beyond.

  // layer 0 (A = x, f32, K=128)
  k_proj<true ><<<dim3(M0_/128, 6, 2), dim3(256), 0, stream>>>(x, nullptr, Wih0, bih0, xg, IN_);
  k_rnn        <<<dim3(4, 2),          dim3(256), 0, stream>>>(xg, Whh0, bhh0, y);
  // layer 1 (A = y, f16, K=512)
  k_proj<false><<<dim3(M0_/128, 6, 2), dim3(256), 0, stream>>>(nullptr, y, Wih, bih, xg, 2*H_);
  k_rnn        <<<dim3(4, 2),          dim3(256), 0, stream>>>(xg, Whh, bhh, y);
  // layer 2
  k_proj<false><<<dim3(M0_/128, 6, 2), dim3(256), 0, stream>>>(nullptr, y, Wih + 1ull*2*G_*(2*H_), bih + 2*G_, xg, 2*H_);
  k_rnn        <<<dim3(4, 2),          dim3(256), 0, stream>>>(xg, Whh + 1ull*2*G_*H_, bhh + 2*G_, y);

  k_head<<<dim3(B_), dim3(256), 0, stream>>>(y, W1, b1, W2, b2, W3, b3, W4, b4,
                                             (float*)d_out);
}

// Round 12
// 1982.846 us; speedup vs baseline: 4.2456x; 4.2456x over previous
//
#include <hip/hip_runtime.h>
#include <stdint.h>

#define B_ 64
#define T_ 512
#define IN_ 128
#define H_ 256
#define G_ 768
#define M0_ (B_*T_)   // 32768

typedef _Float16 f16;
typedef _Float16 f16x2 __attribute__((ext_vector_type(2)));
typedef _Float16 half8 __attribute__((ext_vector_type(8)));
typedef float f32x4 __attribute__((ext_vector_type(4)));

// ---------------- projection GEMM: xg[dir][m][n] = A[m][:]·W[dir][n][:] + bias[dir][n] ----------------
// A: M0 x K (f32 if AF32 else f16) row-major; W: 2 x 768 x K f32 (B^T layout); out: 2 x M0 x 768 f16
template<bool AF32>
__global__ __launch_bounds__(256) void k_proj(
    const float* __restrict__ Af, const f16* __restrict__ Ah,
    const float* __restrict__ W, const float* __restrict__ bias,
    f16* __restrict__ out, int K)
{
  int dir = blockIdx.z;
  const float* Wd = W + (size_t)dir*G_*K;
  const float* bd = bias + dir*G_;
  f16* outd = out + (size_t)dir*M0_*G_;
  int m0 = blockIdx.x*128, n0 = blockIdx.y*128;
  int tid = threadIdx.x, lane = tid & 63, wv = tid >> 6;
  int wm = wv >> 1, wn = wv & 1;
  int l15 = lane & 15, quad = lane >> 4;

  __shared__ f16 As[128][72];   // +8 pad breaks bank conflicts
  __shared__ f16 Ws[128][72];

  f32x4 acc[4][4];
  #pragma unroll
  for (int i = 0; i < 4; i++)
    #pragma unroll
    for (int j = 0; j < 4; j++) acc[i][j] = (f32x4){0.f,0.f,0.f,0.f};

  int lr = tid >> 3, lk = (tid & 7) * 8;
  for (int k0 = 0; k0 < K; k0 += 64){
    #pragma unroll
    for (int it = 0; it < 4; it++){
      int row = lr + it*32;
      // A tile
      if (AF32){
        const float* p = &Af[(size_t)(m0+row)*K + k0 + lk];
        float4 v0 = *(const float4*)p;
        float4 v1 = *(const float4*)(p + 4);
        *(half8*)&As[row][lk] = (half8){(f16)v0.x,(f16)v0.y,(f16)v0.z,(f16)v0.w,
                                        (f16)v1.x,(f16)v1.y,(f16)v1.z,(f16)v1.w};
      } else {
        *(uint4*)&As[row][lk] = *(const uint4*)&Ah[(size_t)(m0+row)*K + k0 + lk];
      }
      // W tile (always f32 -> f16)
      {
        const float* p = &Wd[(size_t)(n0+row)*K + k0 + lk];
        float4 v0 = *(const float4*)p;
        float4 v1 = *(const float4*)(p + 4);
        *(half8*)&Ws[row][lk] = (half8){(f16)v0.x,(f16)v0.y,(f16)v0.z,(f16)v0.w,
                                        (f16)v1.x,(f16)v1.y,(f16)v1.z,(f16)v1.w};
      }
    }
    __syncthreads();
    #pragma unroll
    for (int kk = 0; kk < 64; kk += 32){
      half8 af[4], bf[4];
      #pragma unroll
      for (int mi = 0; mi < 4; mi++) af[mi] = *(const half8*)&As[wm*64 + mi*16 + l15][kk + quad*8];
      #pragma unroll
      for (int ni = 0; ni < 4; ni++) bf[ni] = *(const half8*)&Ws[wn*64 + ni*16 + l15][kk + quad*8];
      #pragma unroll
      for (int mi = 0; mi < 4; mi++)
        #pragma unroll
        for (int ni = 0; ni < 4; ni++)
          acc[mi][ni] = __builtin_amdgcn_mfma_f32_16x16x32_f16(af[mi], bf[ni], acc[mi][ni], 0, 0, 0);
    }
    __syncthreads();
  }
  #pragma unroll
  for (int mi = 0; mi < 4; mi++){
    #pragma unroll
    for (int ni = 0; ni < 4; ni++){
      int m = m0 + wm*64 + mi*16 + quad*4;
      int n = n0 + wn*64 + ni*16 + l15;
      float bn = bd[n];
      #pragma unroll
      for (int r = 0; r < 4; r++)
        outd[(size_t)(m+r)*G_ + n] = (f16)(acc[mi][ni][r] + bn);
    }
  }
}

// ---------------- persistent-register GRU via broadcast-M MFMA, 8 waves @ 2 waves/EU ----------------
// r4's proven structure (590 us: VGPR 128 arch + AGPR weight file, no spill) plus:
//   (a) ping-pong xg register sets via x2-unrolled step loop -- eliminates the per-step
//       cxr=nxr rotate copies and decouples the vmcnt wait (load->use = full step);
//   (b) template<LASTL>: the last layer stores y only at tt == T_-1 (k_head reads only
//       y[:,T-1,:]), deleting 511/512 of that dispatch's store traffic.
// Wave wv owns units [wv*32,wv*32+32): 6 tiles (3 gates x 2 col-tiles) x 8 k-frags
// = 48 half8 B-frags (192 regs, AGPR-resident). Broadcast-M: lane's acc[t][0] is the
// full 256-dot for its column -> no cross-lane reduce. One raw lgkm-only barrier/step.
template<bool LASTL>
__global__ __launch_bounds__(512) __attribute__((amdgpu_waves_per_eu(2, 2)))
void k_rnn(
    const f16* __restrict__ xg, const float* __restrict__ whh,
    const float* __restrict__ bhh, f16* __restrict__ y)
{
  int b = blockIdx.x, dir = blockIdx.y;
  int tid = threadIdx.x, lane = tid & 63, wv = tid >> 6;
  int col = lane & 15, kg = lane >> 4;       // fragment coords: col, k-group of 8
  int u = wv*32 + (lane & 31);               // owned unit (lanes 32-63 mirror 0-31)
  int dsel = (lane >> 4) & 1;                // col-tile select

  const f16* cxg = xg + ((size_t)dir*M0_ + (size_t)b*T_)*G_;
  const float* wbase = whh + (size_t)dir*G_*H_;
  const float* bh = bhh + dir*G_;
  f16* yb = y + (size_t)b*T_*512 + dir*256;

  __shared__ __align__(16) f16 h0buf[256];
  __shared__ __align__(16) f16 h1buf[256];

  // ---- resident B-fragments: tile t = gate*2 + coltile, 8 k-frags each ----
  half8 wf[48];
  #pragma unroll
  for (int t = 0; t < 6; t++){
    int g = t >> 1, c = t & 1;
    const float* wrow = wbase + (size_t)(g*256 + wv*32 + c*16 + col)*H_;
    #pragma unroll
    for (int kf = 0; kf < 8; kf++){
      const float4* p = (const float4*)(wrow + kf*32 + kg*8);
      float4 v0 = p[0], v1 = p[1];
      wf[t*8+kf] = (half8){(f16)v0.x,(f16)v0.y,(f16)v0.z,(f16)v0.w,
                           (f16)v1.x,(f16)v1.y,(f16)v1.z,(f16)v1.w};
    }
  }

  float br = bh[u], bz = bh[u+256], bn = bh[u+512];
  float hreg = 0.f;
  if (tid < 256) h0buf[tid] = (f16)0.f;
  __syncthreads();

  // ping-pong xg register sets (no rotate copies)
  f16 axr, axz, axn, bxr, bxz, bxn;
  {
    int t0 = dir ? (T_-1) : 0;
    const f16* xp = cxg + (size_t)t0*G_ + u;
    axr = xp[0]; axz = xp[256]; axn = xp[512];
  }

#define RSTEP(SRC, DST, XR, XZ, XN, TT)                                         \
  {                                                                             \
    const f16* hp = &SRC[kg*8];                                                 \
    f32x4 acc[6];                                                               \
    half8 acur = *(const half8*)hp;                                             \
    half8 anxt = *(const half8*)(hp + 32);                                      \
    _Pragma("unroll")                                                           \
    for (int kf = 0; kf < 8; kf++){                                             \
      half8 ac = acur;                                                          \
      acur = anxt;                                                              \
      if (kf < 6) anxt = *(const half8*)(hp + (kf+2)*32);                       \
      _Pragma("unroll")                                                         \
      for (int t = 0; t < 6; t++){                                              \
        if (kf == 0)                                                            \
          acc[t] = __builtin_amdgcn_mfma_f32_16x16x32_f16(ac, wf[t*8+kf],       \
                     (f32x4){0.f,0.f,0.f,0.f}, 0, 0, 0);                        \
        else                                                                    \
          acc[t] = __builtin_amdgcn_mfma_f32_16x16x32_f16(ac, wf[t*8+kf],       \
                     acc[t], 0, 0, 0);                                          \
      }                                                                         \
    }                                                                           \
    float sr = dsel ? acc[1][0] : acc[0][0];                                    \
    float sz = dsel ? acc[3][0] : acc[2][0];                                    \
    float sn = dsel ? acc[5][0] : acc[4][0];                                    \
    float ar = (float)(XR) + sr + br; ar = fminf(fmaxf(ar, -30.f), 30.f);       \
    float az = (float)(XZ) + sz + bz; az = fminf(fmaxf(az, -30.f), 30.f);       \
    float r_ = 1.f/(1.f + __expf(-ar));                                         \
    float z_ = 1.f/(1.f + __expf(-az));                                         \
    float an = (float)(XN) + r_*(sn + bn); an = fminf(fmaxf(an, -15.f), 15.f);  \
    float e_ = __expf(2.f*an);                                                  \
    float nn = (e_ - 1.f)/(e_ + 1.f);                                           \
    hreg = (1.f - z_)*nn + z_*hreg;                                             \
    if (lane < 32){                                                             \
      DST[u] = (f16)hreg;                                                       \
      if (!LASTL || (TT) == T_-1)                                               \
        yb[(size_t)(TT)*512 + u] = (f16)hreg;                                   \
    }                                                                           \
    asm volatile("s_waitcnt lgkmcnt(0)\n\ts_barrier" ::: "memory");             \
  }

  for (int s = 0; s < T_; s += 2){
    int ttA = dir ? (T_-1-s) : s;
    int ttB = dir ? (T_-2-s) : (s+1);
    int s2c = (s + 2 < T_) ? (s + 2) : (T_ - 1);   // clamped dummy on last iter
    int ttC = dir ? (T_-1-s2c) : s2c;

    // half A: prefetch set B (step s+1) BEFORE the body; body consumes set A
    {
      const f16* xq = cxg + (size_t)ttB*G_ + u;
      bxr = xq[0]; bxz = xq[256]; bxn = xq[512];
    }
    RSTEP(h0buf, h1buf, axr, axz, axn, ttA)

    // half B: prefetch set A (step s+2); body consumes set B
    {
      const f16* xq = cxg + (size_t)ttC*G_ + u;
      axr = xq[0]; axz = xq[256]; axn = xq[512];
    }
    RSTEP(h1buf, h0buf, bxr, bxz, bxn, ttB)
  }
#undef RSTEP
}

// ---------------- MLP head: one WG per batch, all f32 ----------------
__global__ __launch_bounds__(256) void k_head(
    const f16* __restrict__ y,
    const float* __restrict__ W1, const float* __restrict__ b1,
    const float* __restrict__ W2, const float* __restrict__ b2,
    const float* __restrict__ W3, const float* __restrict__ b3,
    const float* __restrict__ W4, const float* __restrict__ b4,
    float* __restrict__ out)
{
  int b = blockIdx.x, tid = threadIdx.x;
  __shared__ float a0[512], a1[128], a2[64], a3[256];
  const f16* yr = y + ((size_t)b*T_ + (T_-1))*512;
  a0[tid] = (float)yr[tid]; a0[tid+256] = (float)yr[tid+256];
  __syncthreads();
  if (tid < 128){
    float s = b1[tid];
    const float4* w = (const float4*)(W1 + (size_t)tid*512);
    #pragma unroll 8
    for (int c = 0; c < 128; c++){
      float4 v = w[c];
      s += v.x*a0[c*4] + v.y*a0[c*4+1] + v.z*a0[c*4+2] + v.w*a0[c*4+3];
    }
    a1[tid] = fmaxf(s, 0.f);
  }
  __syncthreads();
  if (tid < 64){
    float s = b2[tid];
    const float4* w = (const float4*)(W2 + (size_t)tid*128);
    #pragma unroll
    for (int c = 0; c < 32; c++){
      float4 v = w[c];
      s += v.x*a1[c*4] + v.y*a1[c*4+1] + v.z*a1[c*4+2] + v.w*a1[c*4+3];
    }
    a2[tid] = fmaxf(s, 0.f);
  }
  __syncthreads();
  if (tid < 256){
    float s = b3[tid];
    const float4* w = (const float4*)(W3 + (size_t)tid*64);
    #pragma unroll
    for (int c = 0; c < 16; c++){
      float4 v = w[c];
      s += v.x*a2[c*4] + v.y*a2[c*4+1] + v.z*a2[c*4+2] + v.w*a2[c*4+3];
    }
    a3[tid] = fmaxf(s, 0.f);
  }
  __syncthreads();
  if (tid < 50){
    float s = b4[tid];
    const float4* w = (const float4*)(W4 + (size_t)tid*256);
    #pragma unroll
    for (int c = 0; c < 64; c++){
      float4 v = w[c];
      s += v.x*a3[c*4] + v.y*a3[c*4+1] + v.z*a3[c*4+2] + v.w*a3[c*4+3];
    }
    out[b*50 + tid] = s;
  }
}

extern "C" void kernel_launch(void* const* d_in, const int* in_sizes, int n_in,
                              void* d_out, int out_size, void* d_ws, size_t ws_size,
                              hipStream_t stream)
{
  const float* x    = (const float*)d_in[0];
  const float* Wih0 = (const float*)d_in[1];
  const float* Whh0 = (const float*)d_in[2];
  const float* bih0 = (const float*)d_in[3];
  const float* bhh0 = (const float*)d_in[4];
  const float* Wih  = (const float*)d_in[5];
  const float* Whh  = (const float*)d_in[6];
  const float* bih  = (const float*)d_in[7];
  const float* bhh  = (const float*)d_in[8];
  const float* W1 = (const float*)d_in[9];
  const float* b1 = (const float*)d_in[10];
  const float* W2 = (const float*)d_in[11];
  const float* b2 = (const float*)d_in[12];
  const float* W3 = (const float*)d_in[13];
  const float* b3 = (const float*)d_in[14];
  const float* W4 = (const float*)d_in[15];
  const float* b4 = (const float*)d_in[16];

  char* ws = (char*)d_ws;
  f16* xg = (f16*)ws;                          // 2*M0*768*2 = 100,663,296 B
  f16* y  = (f16*)(ws + 100663296ull);         //   M0*512*2 =  33,554,432 B
  // total exactly 128 MiB; nothing written beyond.

  // layer 0 (A = x, f32, K=128)
  k_proj<true >  <<<dim3(M0_/128, 6, 2), dim3(256), 0, stream>>>(x, nullptr, Wih0, bih0, xg, IN_);
  k_rnn<false>   <<<dim3(B_, 2),         dim3(512), 0, stream>>>(xg, Whh0, bhh0, y);
  // layer 1 (A = y, f16, K=512)
  k_proj<false>  <<<dim3(M0_/128, 6, 2), dim3(256), 0, stream>>>(nullptr, y, Wih, bih, xg, 2*H_);
  k_rnn<false>   <<<dim3(B_, 2),         dim3(512), 0, stream>>>(xg, Whh, bhh, y);
  // layer 2 (y stores elided except tt == T-1; k_head reads only y[:,T-1,:])
  k_proj<false>  <<<dim3(M0_/128, 6, 2), dim3(256), 0, stream>>>(nullptr, y, Wih + 1ull*2*G_*(2*H_), bih + 2*G_, xg, 2*H_);
  k_rnn<true>    <<<dim3(B_, 2),         dim3(512), 0, stream>>>(xg, Whh + 1ull*2*G_*H_, bhh + 2*G_, y);

  k_head<<<dim3(B_), dim3(256), 0, stream>>>(y, W1, b1, W2, b2, W3, b3, W4, b4,
                                             (float*)d_out);
}